// Round 1
// baseline (542.976 us; speedup 1.0000x reference)
//
#include <hip/hip_runtime.h>
#include <hip/hip_bf16.h>
#include <math.h>

#define NN_NODES 2048
#define NE 65536
#define H1C 32
#define H2C 20
#define AW_STRIDE 4194304ull  // N*N

// ---------------- degree count ----------------
__global__ void k_deg(const int* __restrict__ ei, int* __restrict__ deg) {
    int e = blockIdx.x * 256 + threadIdx.x;
    if (e < NE) atomicAdd(&deg[ei[NE + e]], 1);
}

// ---------------- prefix scan of deg + dinv ----------------
__global__ void k_scan(const int* __restrict__ deg, float* __restrict__ dinv,
                       int* __restrict__ off) {
    __shared__ int s[1024];
    int t = threadIdx.x;
    int d0 = deg[2 * t], d1 = deg[2 * t + 1];
    // self-loop included in degree for normalization
    dinv[2 * t]     = rsqrtf((float)(d0 + 1));
    dinv[2 * t + 1] = rsqrtf((float)(d1 + 1));
    s[t] = d0 + d1;
    __syncthreads();
    for (int o = 1; o < 1024; o <<= 1) {
        int add = (t >= o) ? s[t - o] : 0;
        __syncthreads();
        s[t] += add;
        __syncthreads();
    }
    int excl = (t > 0) ? s[t - 1] : 0;
    off[2 * t] = excl;
    off[2 * t + 1] = excl + d0;
    if (t == 1023) off[2048] = s[1023];
}

// ---------------- scatter edges into CSR ----------------
__global__ void k_scatter(const int* __restrict__ ei, const float* __restrict__ dinv,
                          const int* __restrict__ off, int* __restrict__ cnt,
                          int* __restrict__ csr_src, float* __restrict__ csr_norm) {
    int e = blockIdx.x * 256 + threadIdx.x;
    if (e >= NE) return;
    int s = ei[e], d = ei[NE + e];
    int pos = off[d] + atomicAdd(&cnt[d], 1);
    csr_src[pos] = s;
    csr_norm[pos] = dinv[s] * dinv[d];
}

// ---------------- GEMM1: h_tmp[2048,32] = X[2048,2048] @ W1[2048,32] ----------------
// grid = 512 = 64 row-groups x 8 k-chunks; split-K accumulated via atomics (h_tmp pre-zeroed)
__global__ __launch_bounds__(256) void k_gemm1(const float* __restrict__ X,
                                               const float* __restrict__ W1,
                                               float* __restrict__ h_tmp) {
    __shared__ float Xs[32][33];
    __shared__ __align__(16) float Ws[32][32];
    int t = threadIdx.x;
    int rg = blockIdx.x >> 3, kc = blockIdx.x & 7;
    int r0 = rg * 32;
    int r = t >> 3, c4 = (t & 7) * 4;
    float4 acc = {0.f, 0.f, 0.f, 0.f};
    for (int kt = 0; kt < 8; ++kt) {
        int k0 = kc * 256 + kt * 32;
#pragma unroll
        for (int i = 0; i < 4; ++i) {
            int id = t + i * 256;
            int rr = id >> 5, kk = id & 31;
            Xs[rr][kk] = X[(size_t)(r0 + rr) * 2048 + k0 + kk];
            Ws[rr][kk] = W1[(size_t)(k0 + rr) * 32 + kk];
        }
        __syncthreads();
#pragma unroll
        for (int kk = 0; kk < 32; ++kk) {
            float a = Xs[r][kk];
            float4 b = *(const float4*)&Ws[kk][c4];
            acc.x += a * b.x; acc.y += a * b.y; acc.z += a * b.z; acc.w += a * b.w;
        }
        __syncthreads();
    }
    float* dst = &h_tmp[(size_t)(r0 + r) * 32 + c4];
    atomicAdd(dst + 0, acc.x);
    atomicAdd(dst + 1, acc.y);
    atomicAdd(dst + 2, acc.z);
    atomicAdd(dst + 3, acc.w);
}

// ---------------- aggregation: out = relu(bias + self + sum_edges h[src]*norm) ----------------
template <int C>
__global__ __launch_bounds__(256) void k_agg(const float* __restrict__ h,
                                             const float* __restrict__ csr_norm,
                                             const int* __restrict__ csr_src,
                                             const int* __restrict__ off,
                                             const float* __restrict__ dinv,
                                             const float* __restrict__ bias,
                                             float* __restrict__ out) {
    int n = blockIdx.x;
    int t = threadIdx.x;
    int c = t & 31, s = t >> 5;  // 8 edge slices x 32 channel lanes
    __shared__ float red[8][32];
    float acc = 0.f;
    int e0 = off[n], e1 = off[n + 1];
    if (c < C) {
        for (int e = e0 + s; e < e1; e += 8) {
            int src = csr_src[e];
            acc += h[(size_t)src * C + c] * csr_norm[e];
        }
    }
    red[s][c] = acc;
    __syncthreads();
    if (t < 32) {
        float v = red[0][t];
#pragma unroll
        for (int i = 1; i < 8; ++i) v += red[i][t];
        if (t < C) {
            float dn = dinv[n];
            v += h[(size_t)n * C + t] * dn * dn + bias[t];
            out[(size_t)n * C + t] = fmaxf(v, 0.f);
        }
    }
}

// ---------------- GEMM2: h2t[2048,20] = h1[2048,32] @ W2[32,20] ----------------
__global__ __launch_bounds__(256) void k_gemm2(const float* __restrict__ h1,
                                               const float* __restrict__ W2,
                                               float* __restrict__ h2t) {
    __shared__ float Ws[H1C * H2C];  // 640
    int t = threadIdx.x;
    for (int i = t; i < H1C * H2C; i += 256) Ws[i] = W2[i];
    __syncthreads();
    int id = blockIdx.x * 256 + t;  // 160*256 = 40960 = 2048*20 exactly
    int n = id / 20, c = id % 20;
    const float* hr = &h1[(size_t)n * 32];
    float acc = 0.f;
#pragma unroll
    for (int k = 0; k < 32; ++k) acc += hr[k] * Ws[k * 20 + c];
    h2t[(size_t)n * 20 + c] = acc;
}

// ---------------- x_actor sum over nodes ----------------
__global__ __launch_bounds__(640) void k_xa(const float* __restrict__ h2,
                                            float* __restrict__ xa_sum) {
    __shared__ float red[640];
    int t = threadIdx.x;
    int nl = t / 20, c = t % 20;
    int n = blockIdx.x * 32 + nl;
    red[t] = h2[(size_t)n * 20 + c];
    __syncthreads();
    for (int o = 16; o >= 1; o >>= 1) {
        if (nl < o) red[t] += red[(nl + o) * 20 + c];
        __syncthreads();
    }
    if (t < 20) atomicAdd(&xa_sum[t], red[t]);
}

// ---------------- per-row logits + softmax stats (the big HBM sweep) ----------------
__global__ __launch_bounds__(256) void k_rows(const float* __restrict__ aW,
                                              const float* __restrict__ ab,
                                              const float* __restrict__ xa_sum,
                                              float* __restrict__ rowM,
                                              float* __restrict__ rowZ,
                                              int* __restrict__ rowC) {
    __shared__ float xa[20];
    __shared__ float redf[256];
    __shared__ int redi[256];
    int t = threadIdx.x;
    int row = blockIdx.x;
    if (t < 20) xa[t] = xa_sum[t] * (1.0f / 2048.0f);
    __syncthreads();
    size_t base = (size_t)row * 2048;
    float l[8];
#pragma unroll
    for (int u = 0; u < 2; ++u) {
        int j0 = u * 1024 + t * 4;
        float4 acc = *(const float4*)&ab[base + j0];
#pragma unroll
        for (int k = 0; k < 20; ++k) {
            float4 w = *(const float4*)&aW[(size_t)k * AW_STRIDE + base + j0];
            float sv = xa[k];
            acc.x += sv * w.x; acc.y += sv * w.y; acc.z += sv * w.z; acc.w += sv * w.w;
        }
        l[u * 4 + 0] = acc.x; l[u * 4 + 1] = acc.y;
        l[u * 4 + 2] = acc.z; l[u * 4 + 3] = acc.w;
    }
    // thread-local max/argmax (cols visited in increasing order -> strict > keeps first)
    float m = l[0];
    int mi = t * 4;
#pragma unroll
    for (int q = 1; q < 8; ++q) {
        int col = (q >> 2) * 1024 + t * 4 + (q & 3);
        if (l[q] > m) { m = l[q]; mi = col; }
    }
    redf[t] = m; redi[t] = mi;
    __syncthreads();
    for (int o = 128; o >= 1; o >>= 1) {
        if (t < o) {
            float vo = redf[t + o]; int io = redi[t + o];
            if (vo > redf[t] || (vo == redf[t] && io < redi[t])) { redf[t] = vo; redi[t] = io; }
        }
        __syncthreads();
    }
    float M = redf[0];
    int C1 = redi[0];
    __syncthreads();
    float zsum = 0.f;
#pragma unroll
    for (int q = 0; q < 8; ++q) zsum += expf(l[q] - M);
    redf[t] = zsum;
    __syncthreads();
    for (int o = 128; o >= 1; o >>= 1) {
        if (t < o) redf[t] += redf[t + o];
        __syncthreads();
    }
    if (t == 0) { rowM[row] = M; rowZ[row] = redf[0]; rowC[row] = C1; }
}

// ---------------- final: global argmax, prefix argmax, log_probs, critic ----------------
__global__ __launch_bounds__(256) void k_final(const float* __restrict__ rowM,
                                               const float* __restrict__ rowZ,
                                               const int* __restrict__ rowC,
                                               const float* __restrict__ aW,
                                               const float* __restrict__ ab,
                                               const float* __restrict__ xa_sum,
                                               const float* __restrict__ cW,
                                               const float* __restrict__ cb,
                                               float* __restrict__ out) {
    __shared__ float xa[20];
    __shared__ float rf[256];
    __shared__ int ri[256];
    __shared__ float sM1, sZ1;
    __shared__ int sR1, sC1, sR2, sC2;
    int t = threadIdx.x;
    if (t < 20) xa[t] = xa_sum[t] * (1.0f / 2048.0f);
    __syncthreads();

    // Phase A: global best = argmin over rows of Z (row max prob = 1/Z), tie -> lower row
    float z = INFINITY; int zi = 0x7fffffff;
    for (int i = t; i < 2048; i += 256) {
        float v = rowZ[i];
        if (v < z || (v == z && i < zi)) { z = v; zi = i; }
    }
    rf[t] = z; ri[t] = zi;
    __syncthreads();
    for (int o = 128; o >= 1; o >>= 1) {
        if (t < o) {
            float vo = rf[t + o]; int io = ri[t + o];
            if (vo < rf[t] || (vo == rf[t] && io < ri[t])) { rf[t] = vo; ri[t] = io; }
        }
        __syncthreads();
    }
    if (t == 0) {
        sR1 = ri[0]; sC1 = rowC[ri[0]]; sM1 = rowM[ri[0]]; sZ1 = rowZ[ri[0]];
    }
    __syncthreads();
    int r1 = sR1, c1 = sC1;

    // Phase B1: best full row among rows < r1
    z = INFINITY; zi = 0x7fffffff;
    for (int i = t; i < r1; i += 256) {
        float v = rowZ[i];
        if (v < z || (v == z && i < zi)) { z = v; zi = i; }
    }
    __syncthreads();
    rf[t] = z; ri[t] = zi;
    __syncthreads();
    for (int o = 128; o >= 1; o >>= 1) {
        if (t < o) {
            float vo = rf[t + o]; int io = ri[t + o];
            if (vo < rf[t] || (vo == rf[t] && io < ri[t])) { rf[t] = vo; ri[t] = io; }
        }
        __syncthreads();
    }
    float ZP = rf[0]; int iP = ri[0];
    __syncthreads();

    // Phase B2: prefix of row r1 (cols < c1): max logit -> max prob (monotone within row)
    float lm = -INFINITY; int lj = 0x7fffffff;
    size_t base = (size_t)r1 * 2048;
    for (int j = t; j < c1; j += 256) {
        float acc = ab[base + j];
#pragma unroll
        for (int k = 0; k < 20; ++k) acc += xa[k] * aW[(size_t)k * AW_STRIDE + base + j];
        if (acc > lm) { lm = acc; lj = j; }
    }
    rf[t] = lm; ri[t] = lj;
    __syncthreads();
    for (int o = 128; o >= 1; o >>= 1) {
        if (t < o) {
            float vo = rf[t + o]; int io = ri[t + o];
            if (vo > rf[t] || (vo == rf[t] && io < ri[t])) { rf[t] = vo; ri[t] = io; }
        }
        __syncthreads();
    }
    float LB = rf[0]; int jB = ri[0];
    __syncthreads();

    if (t == 0) {
        int r2, c2;
        if (r1 == 0 && c1 == 0) {
            r2 = 0; c2 = 0;  // argmax over all -inf -> index 0
        } else {
            bool hasA = (r1 > 0), hasB = (c1 > 0);
            float pA = hasA ? 1.0f / ZP : -INFINITY;
            float pB = hasB ? expf(LB - sM1) / sZ1 : -INFINITY;
            if (hasB && (!hasA || pB > pA)) { r2 = r1; c2 = jB; }
            else                            { r2 = iP; c2 = rowC[iP]; }
        }
        sR2 = r2; sC2 = c2;
        out[0] = (float)r1; out[1] = (float)c1;
        out[2] = (float)r2; out[3] = (float)c2;
        float cr = 0.f;
#pragma unroll
        for (int k = 0; k < 20; ++k) cr += xa[k] * cW[k];
        out[8] = cr + cb[0];
    }
    __syncthreads();

    // Phase C: log_probs index the FLATTENED probs at {r1,c1,r2,c2} => row 0 of probs
    if (t < 4) {
        int a = (t == 0) ? sR1 : (t == 1) ? sC1 : (t == 2) ? sR2 : sC2;
        float acc = ab[a];
#pragma unroll
        for (int k = 0; k < 20; ++k) acc += xa[k] * aW[(size_t)k * AW_STRIDE + a];
        float lp = (acc - rowM[0]) - logf(rowZ[0]);
        out[4 + t] = -lp;
    }
}

extern "C" void kernel_launch(void* const* d_in, const int* in_sizes, int n_in,
                              void* d_out, int out_size, void* d_ws, size_t ws_size,
                              hipStream_t stream) {
    const float* x  = (const float*)d_in[0];
    const int*   ei = (const int*)d_in[1];
    const float* W1 = (const float*)d_in[2];
    const float* b1 = (const float*)d_in[3];
    const float* W2 = (const float*)d_in[4];
    const float* b2 = (const float*)d_in[5];
    const float* aW = (const float*)d_in[6];
    const float* ab = (const float*)d_in[7];
    const float* cW = (const float*)d_in[8];
    const float* cb = (const float*)d_in[9];
    float* out = (float*)d_out;

    char* p = (char*)d_ws;
    auto alloc = [&](size_t bytes) {
        void* r = (void*)p;
        p += (bytes + 255) & ~(size_t)255;
        return r;
    };
    // zero-init region first (deg, cnt, xa_sum, h_tmp)
    int*   deg    = (int*)alloc(2048 * 4);
    int*   cnt    = (int*)alloc(2048 * 4);
    float* xa_sum = (float*)alloc(64 * 4);
    float* h_tmp  = (float*)alloc(65536 * 4);
    size_t zero_bytes = (size_t)(p - (char*)d_ws);
    float* dinv     = (float*)alloc(2048 * 4);
    int*   csr_off  = (int*)alloc(2049 * 4);
    int*   csr_src  = (int*)alloc(65536 * 4);
    float* csr_norm = (float*)alloc(65536 * 4);
    float* h1       = (float*)alloc(65536 * 4);
    float* h2t      = (float*)alloc(40960 * 4);
    float* h2       = (float*)alloc(40960 * 4);
    float* rowM     = (float*)alloc(2048 * 4);
    float* rowZ     = (float*)alloc(2048 * 4);
    int*   rowC     = (int*)alloc(2048 * 4);

    hipMemsetAsync(d_ws, 0, zero_bytes, stream);
    k_deg<<<NE / 256, 256, 0, stream>>>(ei, deg);
    k_scan<<<1, 1024, 0, stream>>>(deg, dinv, csr_off);
    k_scatter<<<NE / 256, 256, 0, stream>>>(ei, dinv, csr_off, cnt, csr_src, csr_norm);
    k_gemm1<<<512, 256, 0, stream>>>(x, W1, h_tmp);
    k_agg<32><<<2048, 256, 0, stream>>>(h_tmp, csr_norm, csr_src, csr_off, dinv, b1, h1);
    k_gemm2<<<160, 256, 0, stream>>>(h1, W2, h2t);
    k_agg<20><<<2048, 256, 0, stream>>>(h2t, csr_norm, csr_src, csr_off, dinv, b2, h2);
    k_xa<<<64, 640, 0, stream>>>(h2, xa_sum);
    k_rows<<<2048, 256, 0, stream>>>(aW, ab, xa_sum, rowM, rowZ, rowC);
    k_final<<<1, 256, 0, stream>>>(rowM, rowZ, rowC, aW, ab, xa_sum, cW, cb, out);
}